// Round 10
// baseline (278.507 us; speedup 1.0000x reference)
//
#include <hip/hip_runtime.h>
#include <hip/hip_bf16.h>
#include <hip/amd_detail/amd_hip_unsafe_atomics.h>

#define N_EDGES 200000
#define N_NODES 20000
#define N_GRAPHS 128
#define IN_DIM 16
#define EDGE_DIM 8
#define HID 64
#define OUT_DIM 10

__device__ __forceinline__ float rlanef(float v, int l) {
    return __int_as_float(__builtin_amdgcn_readlane(__float_as_int(v), l));
}

// ---------------------------------------------------------------------------
// Kernel A (combo): blocks 0..15 = precompute (fold emb into w3/b3/root_w),
// blocks 16.. = histogram of destination indices.
// ---------------------------------------------------------------------------
__global__ __launch_bounds__(256) void combo_kernel(
    const float* __restrict__ emb, const float* __restrict__ w3,
    const float* __restrict__ b3, const float* __restrict__ root_w,
    const float* __restrict__ conv_b, const int* __restrict__ dst_idx,
    float* __restrict__ W3p, float* __restrict__ b3p, float* __restrict__ r,
    int* __restrict__ counts)
{
    if (blockIdx.x < 16) {
        int t = blockIdx.x * 256 + threadIdx.x;   // 0..4095
        int k = t >> 6;
        int h = t & 63;
        float acc = 0.f;
#pragma unroll
        for (int i = 0; i < IN_DIM; ++i)
            acc = fmaf(emb[i], w3[k * (IN_DIM * HID) + i * HID + h], acc);
        W3p[t] = acc;
        if (t < HID) {
            float a = 0.f, rr = 0.f;
#pragma unroll
            for (int i = 0; i < IN_DIM; ++i) {
                a  = fmaf(emb[i], b3[i * HID + t], a);
                rr = fmaf(emb[i], root_w[i * HID + t], rr);
            }
            b3p[t] = a;
            r[t]   = rr + conv_b[t];
        }
    } else {
        int e = (blockIdx.x - 16) * 256 + threadIdx.x;
        if (e < N_EDGES) atomicAdd(&counts[dst_idx[e]], 1);
    }
}

// ---------------------------------------------------------------------------
// Kernel B: single-block exclusive scan of counts -> start[]/cursor[].
// Wave shfl scan per 1024-chunk with carry (validated round-2 structure).
// ---------------------------------------------------------------------------
__global__ __launch_bounds__(1024) void scan_kernel(
    const int* __restrict__ counts, int* __restrict__ start,
    int* __restrict__ cursor)
{
    __shared__ int wsum[16];
    __shared__ int s_carry;
    const int t    = threadIdx.x;
    const int lane = t & 63;
    const int wid  = t >> 6;
    if (t == 0) s_carry = 0;
    __syncthreads();
    for (int base = 0; base < N_NODES; base += 1024) {
        const int i = base + t;
        const int v = (i < N_NODES) ? counts[i] : 0;
        int incl = v;
#pragma unroll
        for (int off = 1; off < 64; off <<= 1) {
            int u = __shfl_up(incl, off, 64);
            if (lane >= off) incl += u;
        }
        if (lane == 63) wsum[wid] = incl;
        __syncthreads();
        if (wid == 0) {
            int wv = (lane < 16) ? wsum[lane] : 0;
            int wi = wv;
#pragma unroll
            for (int off = 1; off < 16; off <<= 1) {
                int u = __shfl_up(wi, off, 64);
                if (lane >= off) wi += u;
            }
            if (lane < 16) wsum[lane] = wi - wv;   // exclusive wave prefix
        }
        __syncthreads();
        const int carry = s_carry;
        const int excl  = carry + wsum[wid] + incl - v;
        if (i < N_NODES) { start[i] = excl; cursor[i] = excl; }
        __syncthreads();
        if (t == 1023) s_carry = excl + v;
        __syncthreads();
    }
    if (t == 0) start[N_NODES] = N_EDGES;
}

// ---------------------------------------------------------------------------
// Kernel C: scatter edge ids into dst-sorted order.
// ---------------------------------------------------------------------------
__global__ __launch_bounds__(256) void scatter_kernel(
    const int* __restrict__ dst_idx, int* __restrict__ cursor,
    int* __restrict__ eid_sorted)
{
    int e = blockIdx.x * 256 + threadIdx.x;
    if (e < N_EDGES) {
        const int d = dst_idx[e];
        const int p = atomicAdd(&cursor[d], 1);
        eid_sorted[p] = e;
    }
}

// ---------------------------------------------------------------------------
// Kernel D: fused edge MLP + run-accumulated scatter-add into agg.
// Transposed orientation: lane j owns channel j; weight columns in VGPRs;
// activations broadcast via v_readlane, 4 edges per iteration for ILP.
// Wave processes 64 dst-SORTED edges; same-dst runs accumulate in a register
// and flush once per run (256B atomic row), not once per edge.
// ---------------------------------------------------------------------------
__global__ __launch_bounds__(256) void edge_fused_kernel(
    const float* __restrict__ edge_attr, const int* __restrict__ dst_idx,
    const int* __restrict__ eid_sorted,
    const float* __restrict__ w1, const float* __restrict__ b1,
    const float* __restrict__ w2, const float* __restrict__ b2,
    const float* __restrict__ W3p, const float* __restrict__ b3p,
    float* __restrict__ agg)
{
    const int lane = threadIdx.x & 63;
    const int gw   = (blockIdx.x * 256 + threadIdx.x) >> 6;  // global wave id
    const long base = (long)gw * 64;
    if (base >= N_EDGES) return;                             // 200000 = 3125*64
    const int j = lane;                                      // output channel

    // per-lane weight columns (coalesced: lane j reads column j)
    float w1c[EDGE_DIM], w2c[HID], w3c[HID];
#pragma unroll
    for (int k = 0; k < EDGE_DIM; ++k) w1c[k] = w1[k * HID + j];
#pragma unroll
    for (int k = 0; k < HID; ++k) w2c[k] = w2[k * HID + j];
#pragma unroll
    for (int k = 0; k < HID; ++k) w3c[k] = W3p[k * HID + j];
    const float b1j = b1[j], b2j = b2[j], b3j = b3p[j];

    // my lane's sorted slot: edge id, dst, attrs
    const int  eid    = eid_sorted[base + lane];
    const int  d_mine = dst_idx[eid];
    float ea[EDGE_DIM];
    {
        const float4 a0 = *(const float4*)&edge_attr[(long)eid * EDGE_DIM + 0];
        const float4 a1 = *(const float4*)&edge_attr[(long)eid * EDGE_DIM + 4];
        ea[0] = a0.x; ea[1] = a0.y; ea[2] = a0.z; ea[3] = a0.w;
        ea[4] = a1.x; ea[5] = a1.y; ea[6] = a1.z; ea[7] = a1.w;
    }

    int   cur  = __builtin_amdgcn_readlane(d_mine, 0);
    float macc = 0.f;

#pragma unroll 1
    for (int e = 0; e < 64; e += 4) {
        // ---- L1: h = relu(ea @ w1 + b1), 4 edges ----
        float A0 = b1j, A1 = b1j, A2 = b1j, A3 = b1j;
#pragma unroll
        for (int k = 0; k < EDGE_DIM; ++k) {
            const float s0 = rlanef(ea[k], e + 0);
            const float s1 = rlanef(ea[k], e + 1);
            const float s2 = rlanef(ea[k], e + 2);
            const float s3 = rlanef(ea[k], e + 3);
            A0 = fmaf(s0, w1c[k], A0);
            A1 = fmaf(s1, w1c[k], A1);
            A2 = fmaf(s2, w1c[k], A2);
            A3 = fmaf(s3, w1c[k], A3);
        }
        const float H0 = fmaxf(A0, 0.f), H1 = fmaxf(A1, 0.f);
        const float H2 = fmaxf(A2, 0.f), H3 = fmaxf(A3, 0.f);

        // ---- L2: g = relu(h @ w2 + b2) ----
        A0 = b2j; A1 = b2j; A2 = b2j; A3 = b2j;
#pragma unroll
        for (int k = 0; k < HID; ++k) {
            const float s0 = rlanef(H0, k);
            const float s1 = rlanef(H1, k);
            const float s2 = rlanef(H2, k);
            const float s3 = rlanef(H3, k);
            A0 = fmaf(s0, w2c[k], A0);
            A1 = fmaf(s1, w2c[k], A1);
            A2 = fmaf(s2, w2c[k], A2);
            A3 = fmaf(s3, w2c[k], A3);
        }
        const float G0 = fmaxf(A0, 0.f), G1 = fmaxf(A1, 0.f);
        const float G2 = fmaxf(A2, 0.f), G3 = fmaxf(A3, 0.f);

        // ---- L3: msg = g @ W3p + b3p ----
        A0 = b3j; A1 = b3j; A2 = b3j; A3 = b3j;
#pragma unroll
        for (int k = 0; k < HID; ++k) {
            const float s0 = rlanef(G0, k);
            const float s1 = rlanef(G1, k);
            const float s2 = rlanef(G2, k);
            const float s3 = rlanef(G3, k);
            A0 = fmaf(s0, w3c[k], A0);
            A1 = fmaf(s1, w3c[k], A1);
            A2 = fmaf(s2, w3c[k], A2);
            A3 = fmaf(s3, w3c[k], A3);
        }

        // ---- run-accumulate / flush (dst-sorted, wave-uniform branches) ----
#pragma unroll
        for (int i = 0; i < 4; ++i) {
            const float Ai = (i == 0) ? A0 : (i == 1) ? A1 : (i == 2) ? A2 : A3;
            const int   di = __builtin_amdgcn_readlane(d_mine, e + i);
            if (di != cur) {
                unsafeAtomicAdd(&agg[(long)cur * HID + j], macc);
                macc = Ai;
                cur  = di;
            } else {
                macc += Ai;
            }
        }
    }
    unsafeAtomicAdd(&agg[(long)cur * HID + j], macc);
}

// ---------------------------------------------------------------------------
// Kernel E: out = relu(agg + r), pooled per-graph sums/counts (batch sorted).
// One wave (64 ch) per 128-node chunk, run accumulation per graph id.
// ---------------------------------------------------------------------------
#define NODES_PER_BLOCK 128
__global__ __launch_bounds__(64) void node_kernel(
    const float* __restrict__ agg, const float* __restrict__ r,
    const int* __restrict__ batch,
    float* __restrict__ sums, float* __restrict__ counts_f)
{
    const int j  = threadIdx.x;           // hid channel
    const int n0 = blockIdx.x * NODES_PER_BLOCK;
    const int n1 = min(n0 + NODES_PER_BLOCK, N_NODES);
    if (n0 >= N_NODES) return;
    const float rj = r[j];

    int   g   = batch[n0];
    float acc = 0.f;
    float cnt = 0.f;
    for (int n = n0; n < n1; ++n) {
        const int gn = batch[n];          // wave-uniform
        if (gn != g) {
            unsafeAtomicAdd(&sums[g * HID + j], acc);
            if (j == 0) unsafeAtomicAdd(&counts_f[g], cnt);
            g = gn; acc = 0.f; cnt = 0.f;
        }
        acc += fmaxf(agg[(long)n * HID + j] + rj, 0.f);
        cnt += 1.f;
    }
    unsafeAtomicAdd(&sums[g * HID + j], acc);
    if (j == 0) unsafeAtomicAdd(&counts_f[g], cnt);
}

// ---------------------------------------------------------------------------
// Kernel F: classifier head. One block (128 threads) per graph.
// ---------------------------------------------------------------------------
__global__ __launch_bounds__(128) void head_kernel(
    const float* __restrict__ sums, const float* __restrict__ counts,
    const float* __restrict__ l1_w, const float* __restrict__ l1_b,
    const float* __restrict__ l2_w, const float* __restrict__ l2_b,
    float* __restrict__ out)
{
    const int g = blockIdx.x;
    const int t = threadIdx.x;
    __shared__ float pooled[HID];
    __shared__ float hid[2 * HID];

    const float cnt = fmaxf(counts[g], 1.0f);
    if (t < HID) pooled[t] = sums[g * HID + t] / cnt;
    __syncthreads();

    float a = l1_b[t];
#pragma unroll
    for (int k = 0; k < HID; ++k)
        a = fmaf(pooled[k], l1_w[k * (2 * HID) + t], a);
    hid[t] = fmaxf(a, 0.f);
    __syncthreads();

    if (t < OUT_DIM) {
        float o = l2_b[t];
#pragma unroll
        for (int k = 0; k < 2 * HID; ++k)
            o = fmaf(hid[k], l2_w[k * OUT_DIM + t], o);
        out[g * OUT_DIM + t] = o;
    }
}

// ---------------------------------------------------------------------------
extern "C" void kernel_launch(void* const* d_in, const int* in_sizes, int n_in,
                              void* d_out, int out_size, void* d_ws, size_t ws_size,
                              hipStream_t stream) {
    const float* edge_attr = (const float*)d_in[0];
    const int*   edge_idx  = (const int*)d_in[1];
    const int*   batch     = (const int*)d_in[2];
    const float* node_emb  = (const float*)d_in[3];
    const float* w1        = (const float*)d_in[4];
    const float* b1        = (const float*)d_in[5];
    const float* w2        = (const float*)d_in[6];
    const float* b2        = (const float*)d_in[7];
    const float* w3        = (const float*)d_in[8];
    const float* b3        = (const float*)d_in[9];
    const float* root_w    = (const float*)d_in[10];
    const float* conv_b    = (const float*)d_in[11];
    const float* l1_w      = (const float*)d_in[12];
    const float* l1_b      = (const float*)d_in[13];
    const float* l2_w      = (const float*)d_in[14];
    const float* l2_b      = (const float*)d_in[15];
    float* out = (float*)d_out;

    // workspace layout (floats / ints)
    float* ws     = (float*)d_ws;
    float* W3p    = ws;                          // 4096
    float* b3p    = W3p + HID * HID;             // 64
    float* r      = b3p + HID;                   // 64
    float* sums   = r + HID;                     // 128*64 = 8192
    float* cts    = sums + N_GRAPHS * HID;       // 128
    int*   counts = (int*)(cts + N_GRAPHS);      // 20000
    int*   startp = counts + N_NODES;            // 20001
    int*   cursor = startp + (N_NODES + 1);      // 20000
    int*   eid    = cursor + N_NODES;            // 200000
    float* agg    = (float*)(eid + N_EDGES);     // 20000*64 = 1,280,000

    // zero sums/cts/counts (contiguous) and agg
    hipMemsetAsync(sums, 0,
                   (size_t)(N_GRAPHS * HID + N_GRAPHS + N_NODES) * 4, stream);
    hipMemsetAsync(agg, 0, (size_t)N_NODES * HID * 4, stream);

    const int* dst_idx = edge_idx + N_EDGES;   // edge_index[1]

    combo_kernel<<<16 + (N_EDGES + 255) / 256, 256, 0, stream>>>(
        node_emb, w3, b3, root_w, conv_b, dst_idx, W3p, b3p, r, counts);

    scan_kernel<<<1, 1024, 0, stream>>>(counts, startp, cursor);

    scatter_kernel<<<(N_EDGES + 255) / 256, 256, 0, stream>>>(
        dst_idx, cursor, eid);

    edge_fused_kernel<<<(N_EDGES / 64 + 3) / 4, 256, 0, stream>>>(
        edge_attr, dst_idx, eid, w1, b1, w2, b2, W3p, b3p, agg);

    node_kernel<<<(N_NODES + NODES_PER_BLOCK - 1) / NODES_PER_BLOCK, 64, 0, stream>>>(
        agg, r, batch, sums, cts);

    head_kernel<<<N_GRAPHS, 128, 0, stream>>>(
        sums, cts, l1_w, l1_b, l2_w, l2_b, out);
}

// Round 11
// 229.636 us; speedup vs baseline: 1.2128x; 1.2128x over previous
//
#include <hip/hip_runtime.h>
#include <hip/hip_bf16.h>
#include <hip/amd_detail/amd_hip_unsafe_atomics.h>

#define N_EDGES 200000
#define N_NODES 20000
#define N_GRAPHS 128
#define IN_DIM 16
#define EDGE_DIM 8
#define HID 64
#define OUT_DIM 10
#define SCAN_NBLK ((N_NODES + 1023) / 1024)   // 20

__device__ __forceinline__ float rlanef(float v, int l) {
    return __int_as_float(__builtin_amdgcn_readlane(__float_as_int(v), l));
}

// ---------------------------------------------------------------------------
// Kernel A (combo): blocks 0..15 = precompute (fold emb into w3/b3/root_w),
// blocks 16.. = histogram of destination indices.
// ---------------------------------------------------------------------------
__global__ __launch_bounds__(256) void combo_kernel(
    const float* __restrict__ emb, const float* __restrict__ w3,
    const float* __restrict__ b3, const float* __restrict__ root_w,
    const float* __restrict__ conv_b, const int* __restrict__ dst_idx,
    float* __restrict__ W3p, float* __restrict__ b3p, float* __restrict__ r,
    int* __restrict__ counts)
{
    if (blockIdx.x < 16) {
        int t = blockIdx.x * 256 + threadIdx.x;   // 0..4095
        int k = t >> 6;
        int h = t & 63;
        float acc = 0.f;
#pragma unroll
        for (int i = 0; i < IN_DIM; ++i)
            acc = fmaf(emb[i], w3[k * (IN_DIM * HID) + i * HID + h], acc);
        W3p[t] = acc;
        if (t < HID) {
            float a = 0.f, rr = 0.f;
#pragma unroll
            for (int i = 0; i < IN_DIM; ++i) {
                a  = fmaf(emb[i], b3[i * HID + t], a);
                rr = fmaf(emb[i], root_w[i * HID + t], rr);
            }
            b3p[t] = a;
            r[t]   = rr + conv_b[t];
        }
    } else {
        int e = (blockIdx.x - 16) * 256 + threadIdx.x;
        if (e < N_EDGES) atomicAdd(&counts[dst_idx[e]], 1);
    }
}

// ---------------------------------------------------------------------------
// Kernel 2a/2b/2c: multi-block exclusive scan of counts -> start[]/cursor[].
// ---------------------------------------------------------------------------
__global__ __launch_bounds__(1024) void scanA_kernel(
    const int* __restrict__ counts, int* __restrict__ start, int* __restrict__ tot)
{
    const int b = blockIdx.x, t = threadIdx.x;
    const int i = b * 1024 + t;
    const int v = (i < N_NODES) ? counts[i] : 0;
    const int lane = t & 63, wid = t >> 6;
    __shared__ int wsum[16];
    int incl = v;
#pragma unroll
    for (int off = 1; off < 64; off <<= 1) {
        int u = __shfl_up(incl, off, 64);
        if (lane >= off) incl += u;
    }
    if (lane == 63) wsum[wid] = incl;
    __syncthreads();
    if (wid == 0) {
        int wv = (lane < 16) ? wsum[lane] : 0;
        int wi = wv;
#pragma unroll
        for (int off = 1; off < 16; off <<= 1) {
            int u = __shfl_up(wi, off, 64);
            if (lane >= off) wi += u;
        }
        if (lane < 16) wsum[lane] = wi - wv;   // exclusive wave prefix
    }
    __syncthreads();
    const int excl = wsum[wid] + incl - v;     // block-local exclusive prefix
    if (i < N_NODES) start[i] = excl;
    if (t == 1023) tot[b] = excl + v;          // block total
}

__global__ __launch_bounds__(64) void scanB_kernel(int* __restrict__ tot,
                                                   int* __restrict__ off)
{
    const int t = threadIdx.x;
    int v = (t < SCAN_NBLK) ? tot[t] : 0;
    int incl = v;
#pragma unroll
    for (int o = 1; o < 64; o <<= 1) {
        int u = __shfl_up(incl, o, 64);
        if (t >= o) incl += u;
    }
    if (t < SCAN_NBLK) off[t] = incl - v;      // exclusive
}

__global__ __launch_bounds__(1024) void scanC_kernel(
    int* __restrict__ start, int* __restrict__ cursor, const int* __restrict__ off)
{
    const int b = blockIdx.x, t = threadIdx.x;
    const int i = b * 1024 + t;
    if (i < N_NODES) {
        const int s = start[i] + off[b];
        start[i]  = s;
        cursor[i] = s;
    }
    if (b == 0 && t == 0) start[N_NODES] = N_EDGES;
}

// ---------------------------------------------------------------------------
// Kernel D: per-edge MLP, transposed: lane j owns output channel j; weight
// columns in VGPRs; ACTIVATIONS broadcast via LDS (wave-uniform float4
// ds_read = conflict-free broadcast, 1 LDS op per 4 FMAs, LDS pipe runs
// parallel to VALU). 2 edges per iteration, 2 split accumulators each.
// Writes msg row into dst-sorted slot via per-lane cursor slot.
// ---------------------------------------------------------------------------
#define EW_WAVES 4
__global__ __launch_bounds__(256) void edge_kernel(
    const float* __restrict__ edge_attr, const int* __restrict__ dst_idx,
    const float* __restrict__ w1, const float* __restrict__ b1,
    const float* __restrict__ w2, const float* __restrict__ b2,
    const float* __restrict__ W3p, const float* __restrict__ b3p,
    int* __restrict__ cursor, float* __restrict__ msg_buf)
{
    const int lane = threadIdx.x & 63;
    const int wv   = threadIdx.x >> 6;                       // wave in block
    const int gw   = blockIdx.x * EW_WAVES + wv;             // global wave id
    const long base = (long)gw * 64;
    if (base >= N_EDGES) return;                             // 200000 = 3125*64
    const int j = lane;                                      // output channel

    __shared__ __align__(16) float s_h[EW_WAVES][2][HID];
    __shared__ __align__(16) float s_g[EW_WAVES][2][HID];
    float* __restrict__ sh0 = s_h[wv][0];
    float* __restrict__ sh1 = s_h[wv][1];
    float* __restrict__ sg0 = s_g[wv][0];
    float* __restrict__ sg1 = s_g[wv][1];

    // per-lane weight columns (coalesced: lane j reads column j)
    float w1c[EDGE_DIM], w2c[HID], w3c[HID];
#pragma unroll
    for (int k = 0; k < EDGE_DIM; ++k) w1c[k] = w1[k * HID + j];
#pragma unroll
    for (int k = 0; k < HID; ++k) w2c[k] = w2[k * HID + j];
#pragma unroll
    for (int k = 0; k < HID; ++k) w3c[k] = W3p[k * HID + j];
    const float b1j = b1[j], b2j = b2[j], b3j = b3p[j];

    // my lane's edge: attrs, dst, sorted slot (one atomic instr per wave)
    const long e_mine = base + lane;
    float ea[EDGE_DIM];
    {
        const float4 a0 = *(const float4*)&edge_attr[e_mine * EDGE_DIM + 0];
        const float4 a1 = *(const float4*)&edge_attr[e_mine * EDGE_DIM + 4];
        ea[0] = a0.x; ea[1] = a0.y; ea[2] = a0.z; ea[3] = a0.w;
        ea[4] = a1.x; ea[5] = a1.y; ea[6] = a1.z; ea[7] = a1.w;
    }
    const int d_mine = dst_idx[e_mine];
    const int p_mine = atomicAdd(&cursor[d_mine], 1);

#pragma unroll 1
    for (int e = 0; e < 64; e += 2) {
        // ---- L1: h = relu(ea @ w1 + b1)  (readlane: only 8 k-values) ----
        float A0 = b1j, A1 = b1j;
#pragma unroll
        for (int k = 0; k < EDGE_DIM; ++k) {
            A0 = fmaf(rlanef(ea[k], e),     w1c[k], A0);
            A1 = fmaf(rlanef(ea[k], e + 1), w1c[k], A1);
        }
        sh0[j] = fmaxf(A0, 0.f);
        sh1[j] = fmaxf(A1, 0.f);

        // ---- L2: g = relu(h @ w2 + b2), h via LDS float4 broadcast ----
        float B0a = b2j, B0b = 0.f, B1a = b2j, B1b = 0.f;
#pragma unroll
        for (int kk = 0; kk < HID / 4; ++kk) {
            const float4 h0 = *(const float4*)&sh0[kk * 4];
            const float4 h1 = *(const float4*)&sh1[kk * 4];
            B0a = fmaf(h0.x, w2c[kk * 4 + 0], B0a);
            B0b = fmaf(h0.y, w2c[kk * 4 + 1], B0b);
            B0a = fmaf(h0.z, w2c[kk * 4 + 2], B0a);
            B0b = fmaf(h0.w, w2c[kk * 4 + 3], B0b);
            B1a = fmaf(h1.x, w2c[kk * 4 + 0], B1a);
            B1b = fmaf(h1.y, w2c[kk * 4 + 1], B1b);
            B1a = fmaf(h1.z, w2c[kk * 4 + 2], B1a);
            B1b = fmaf(h1.w, w2c[kk * 4 + 3], B1b);
        }
        sg0[j] = fmaxf(B0a + B0b, 0.f);
        sg1[j] = fmaxf(B1a + B1b, 0.f);

        // ---- L3: msg = g @ W3p + b3p, g via LDS float4 broadcast ----
        float C0a = b3j, C0b = 0.f, C1a = b3j, C1b = 0.f;
#pragma unroll
        for (int kk = 0; kk < HID / 4; ++kk) {
            const float4 g0 = *(const float4*)&sg0[kk * 4];
            const float4 g1 = *(const float4*)&sg1[kk * 4];
            C0a = fmaf(g0.x, w3c[kk * 4 + 0], C0a);
            C0b = fmaf(g0.y, w3c[kk * 4 + 1], C0b);
            C0a = fmaf(g0.z, w3c[kk * 4 + 2], C0a);
            C0b = fmaf(g0.w, w3c[kk * 4 + 3], C0b);
            C1a = fmaf(g1.x, w3c[kk * 4 + 0], C1a);
            C1b = fmaf(g1.y, w3c[kk * 4 + 1], C1b);
            C1a = fmaf(g1.z, w3c[kk * 4 + 2], C1a);
            C1b = fmaf(g1.w, w3c[kk * 4 + 3], C1b);
        }
        const float M0 = C0a + C0b;
        const float M1 = C1a + C1b;

        // ---- store into dst-sorted slots (256B contiguous per edge) ----
        const int p0 = __builtin_amdgcn_readlane(p_mine, e);
        const int p1 = __builtin_amdgcn_readlane(p_mine, e + 1);
        msg_buf[(long)p0 * HID + j] = M0;
        msg_buf[(long)p1 * HID + j] = M1;
    }
}

// ---------------------------------------------------------------------------
// Kernel E: gather msg rows per node, +r, relu, per-graph pooled sums/counts.
// One wave per 8 nodes; lane = hid channel; batch sorted -> run accumulation.
// ---------------------------------------------------------------------------
#define GN_PER_WAVE 8
__global__ __launch_bounds__(256) void gather_kernel(
    const float* __restrict__ msg_buf, const int* __restrict__ start,
    const float* __restrict__ r, const int* __restrict__ batch,
    float* __restrict__ sums, float* __restrict__ counts_f)
{
    const int wave = threadIdx.x >> 6;
    const int j    = threadIdx.x & 63;
    const int n0   = blockIdx.x * (4 * GN_PER_WAVE) + wave * GN_PER_WAVE;
    if (n0 >= N_NODES) return;
    const int n1 = min(n0 + GN_PER_WAVE, N_NODES);
    const float rj = r[j];

    int   g    = batch[n0];
    float pacc = 0.f, cnt = 0.f;
    for (int n = n0; n < n1; ++n) {
        const int gn = batch[n];
        if (gn != g) {
            unsafeAtomicAdd(&sums[g * HID + j], pacc);
            if (j == 0) unsafeAtomicAdd(&counts_f[g], cnt);
            g = gn; pacc = 0.f; cnt = 0.f;
        }
        float acc = 0.f;
        const int p0 = start[n], p1 = start[n + 1];
        for (int p = p0; p < p1; ++p)
            acc += msg_buf[(long)p * HID + j];
        pacc += fmaxf(acc + rj, 0.f);
        cnt  += 1.f;
    }
    unsafeAtomicAdd(&sums[g * HID + j], pacc);
    if (j == 0) unsafeAtomicAdd(&counts_f[g], cnt);
}

// ---------------------------------------------------------------------------
// Kernel F: classifier head. One block (128 threads) per graph.
// ---------------------------------------------------------------------------
__global__ __launch_bounds__(128) void head_kernel(
    const float* __restrict__ sums, const float* __restrict__ counts,
    const float* __restrict__ l1_w, const float* __restrict__ l1_b,
    const float* __restrict__ l2_w, const float* __restrict__ l2_b,
    float* __restrict__ out)
{
    const int g = blockIdx.x;
    const int t = threadIdx.x;
    __shared__ float pooled[HID];
    __shared__ float hid[2 * HID];

    const float cnt = fmaxf(counts[g], 1.0f);
    if (t < HID) pooled[t] = sums[g * HID + t] / cnt;
    __syncthreads();

    float a = l1_b[t];
#pragma unroll
    for (int k = 0; k < HID; ++k)
        a = fmaf(pooled[k], l1_w[k * (2 * HID) + t], a);
    hid[t] = fmaxf(a, 0.f);
    __syncthreads();

    if (t < OUT_DIM) {
        float o = l2_b[t];
#pragma unroll
        for (int k = 0; k < 2 * HID; ++k)
            o = fmaf(hid[k], l2_w[k * OUT_DIM + t], o);
        out[g * OUT_DIM + t] = o;
    }
}

// ---------------------------------------------------------------------------
extern "C" void kernel_launch(void* const* d_in, const int* in_sizes, int n_in,
                              void* d_out, int out_size, void* d_ws, size_t ws_size,
                              hipStream_t stream) {
    const float* edge_attr = (const float*)d_in[0];
    const int*   edge_idx  = (const int*)d_in[1];
    const int*   batch     = (const int*)d_in[2];
    const float* node_emb  = (const float*)d_in[3];
    const float* w1        = (const float*)d_in[4];
    const float* b1        = (const float*)d_in[5];
    const float* w2        = (const float*)d_in[6];
    const float* b2        = (const float*)d_in[7];
    const float* w3        = (const float*)d_in[8];
    const float* b3        = (const float*)d_in[9];
    const float* root_w    = (const float*)d_in[10];
    const float* conv_b    = (const float*)d_in[11];
    const float* l1_w      = (const float*)d_in[12];
    const float* l1_b      = (const float*)d_in[13];
    const float* l2_w      = (const float*)d_in[14];
    const float* l2_b      = (const float*)d_in[15];
    float* out = (float*)d_out;

    // workspace layout
    float* ws     = (float*)d_ws;
    float* W3p    = ws;                          // 4096
    float* b3p    = W3p + HID * HID;             // 64
    float* r      = b3p + HID;                   // 64
    float* sums   = r + HID;                     // 128*64
    float* cts    = sums + N_GRAPHS * HID;       // 128
    int*   counts = (int*)(cts + N_GRAPHS);      // 20000
    int*   startp = counts + N_NODES;            // 20001
    int*   cursor = startp + (N_NODES + 1);      // 20000
    int*   tot    = cursor + N_NODES;            // 20
    int*   off    = tot + SCAN_NBLK;             // 20
    float* msg    = (float*)(off + SCAN_NBLK);   // 200000*64 floats (51.2 MB)

    // zero sums/cts/counts (contiguous region)
    hipMemsetAsync(sums, 0,
                   (size_t)(N_GRAPHS * HID + N_GRAPHS + N_NODES) * 4, stream);

    const int* dst_idx = edge_idx + N_EDGES;   // edge_index[1]

    combo_kernel<<<16 + (N_EDGES + 255) / 256, 256, 0, stream>>>(
        node_emb, w3, b3, root_w, conv_b, dst_idx, W3p, b3p, r, counts);

    scanA_kernel<<<SCAN_NBLK, 1024, 0, stream>>>(counts, startp, tot);
    scanB_kernel<<<1, 64, 0, stream>>>(tot, off);
    scanC_kernel<<<SCAN_NBLK, 1024, 0, stream>>>(startp, cursor, off);

    edge_kernel<<<(N_EDGES / 64 + EW_WAVES - 1) / EW_WAVES, 64 * EW_WAVES, 0, stream>>>(
        edge_attr, dst_idx, w1, b1, w2, b2, W3p, b3p, cursor, msg);

    gather_kernel<<<(N_NODES + 4 * GN_PER_WAVE - 1) / (4 * GN_PER_WAVE), 256, 0, stream>>>(
        msg, startp, r, batch, sums, cts);

    head_kernel<<<N_GRAPHS, 128, 0, stream>>>(
        sums, cts, l1_w, l1_b, l2_w, l2_b, out);
}

// Round 13
// 152.879 us; speedup vs baseline: 1.8217x; 1.5021x over previous
//
#include <hip/hip_runtime.h>
#include <hip/hip_bf16.h>
#include <hip/amd_detail/amd_hip_unsafe_atomics.h>

#define N_EDGES 200000
#define N_NODES 20000
#define N_GRAPHS 128
#define IN_DIM 16
#define EDGE_DIM 8
#define HID 64
#define OUT_DIM 10
#define SCAN_NBLK ((N_NODES + 1023) / 1024)   // 20

__device__ __forceinline__ float rlanef(float v, int l) {
    return __int_as_float(__builtin_amdgcn_readlane(__float_as_int(v), l));
}

// ---------------------------------------------------------------------------
// Kernel A (combo): blocks 0..15 = precompute (fold emb into w3/b3/root_w),
// blocks 16.. = histogram of destination indices.
// ---------------------------------------------------------------------------
__global__ __launch_bounds__(256) void combo_kernel(
    const float* __restrict__ emb, const float* __restrict__ w3,
    const float* __restrict__ b3, const float* __restrict__ root_w,
    const float* __restrict__ conv_b, const int* __restrict__ dst_idx,
    float* __restrict__ W3p, float* __restrict__ b3p, float* __restrict__ r,
    int* __restrict__ counts)
{
    if (blockIdx.x < 16) {
        int t = blockIdx.x * 256 + threadIdx.x;   // 0..4095
        int k = t >> 6;
        int h = t & 63;
        float acc = 0.f;
#pragma unroll
        for (int i = 0; i < IN_DIM; ++i)
            acc = fmaf(emb[i], w3[k * (IN_DIM * HID) + i * HID + h], acc);
        W3p[t] = acc;
        if (t < HID) {
            float a = 0.f, rr = 0.f;
#pragma unroll
            for (int i = 0; i < IN_DIM; ++i) {
                a  = fmaf(emb[i], b3[i * HID + t], a);
                rr = fmaf(emb[i], root_w[i * HID + t], rr);
            }
            b3p[t] = a;
            r[t]   = rr + conv_b[t];
        }
    } else {
        int e = (blockIdx.x - 16) * 256 + threadIdx.x;
        if (e < N_EDGES) atomicAdd(&counts[dst_idx[e]], 1);
    }
}

// ---------------------------------------------------------------------------
// Kernel 2a/2b/2c: multi-block exclusive scan of counts -> start[]/cursor[].
// ---------------------------------------------------------------------------
__global__ __launch_bounds__(1024) void scanA_kernel(
    const int* __restrict__ counts, int* __restrict__ start, int* __restrict__ tot)
{
    const int b = blockIdx.x, t = threadIdx.x;
    const int i = b * 1024 + t;
    const int v = (i < N_NODES) ? counts[i] : 0;
    const int lane = t & 63, wid = t >> 6;
    __shared__ int wsum[16];
    int incl = v;
#pragma unroll
    for (int off = 1; off < 64; off <<= 1) {
        int u = __shfl_up(incl, off, 64);
        if (lane >= off) incl += u;
    }
    if (lane == 63) wsum[wid] = incl;
    __syncthreads();
    if (wid == 0) {
        int wv = (lane < 16) ? wsum[lane] : 0;
        int wi = wv;
#pragma unroll
        for (int off = 1; off < 16; off <<= 1) {
            int u = __shfl_up(wi, off, 64);
            if (lane >= off) wi += u;
        }
        if (lane < 16) wsum[lane] = wi - wv;   // exclusive wave prefix
    }
    __syncthreads();
    const int excl = wsum[wid] + incl - v;     // block-local exclusive prefix
    if (i < N_NODES) start[i] = excl;
    if (t == 1023) tot[b] = excl + v;          // block total
}

__global__ __launch_bounds__(64) void scanB_kernel(int* __restrict__ tot,
                                                   int* __restrict__ off)
{
    const int t = threadIdx.x;
    int v = (t < SCAN_NBLK) ? tot[t] : 0;
    int incl = v;
#pragma unroll
    for (int o = 1; o < 64; o <<= 1) {
        int u = __shfl_up(incl, o, 64);
        if (t >= o) incl += u;
    }
    if (t < SCAN_NBLK) off[t] = incl - v;      // exclusive
}

__global__ __launch_bounds__(1024) void scanC_kernel(
    int* __restrict__ start, int* __restrict__ cursor, const int* __restrict__ off)
{
    const int b = blockIdx.x, t = threadIdx.x;
    const int i = b * 1024 + t;
    if (i < N_NODES) {
        const int s = start[i] + off[b];
        start[i]  = s;
        cursor[i] = s;
    }
    if (b == 0 && t == 0) start[N_NODES] = N_EDGES;
}

// ---------------------------------------------------------------------------
// Kernel D: per-edge MLP, transposed (lane j = output channel j), TWO-PHASE:
//   phase A: L1 (readlane bcast) + L2 (LDS b128 bcast) -> h2 into LDS
//   phase B: L3 (LDS b128 bcast) -> msg stores
// Only ONE 64-float weight-column set is live per phase; asm pins force the
// columns to stay VGPR-resident (R10's VGPR=84 showed the compiler reloads
// them from global otherwise). EPW=16 edges/wave -> 3125 blocks for TLP.
// ---------------------------------------------------------------------------
#define EPW 16
#define EW_WAVES 4
__global__ __launch_bounds__(256) void edge_kernel(
    const float* __restrict__ edge_attr, const int* __restrict__ dst_idx,
    const float* __restrict__ w1, const float* __restrict__ b1,
    const float* __restrict__ w2, const float* __restrict__ b2,
    const float* __restrict__ W3p, const float* __restrict__ b3p,
    int* __restrict__ cursor, float* __restrict__ msg_buf)
{
    const int lane = threadIdx.x & 63;
    const int wv   = threadIdx.x >> 6;                       // wave in block
    const int gw   = blockIdx.x * EW_WAVES + wv;             // global wave id
    const long base = (long)gw * EPW;
    if (base >= N_EDGES) return;                             // 200000 = 12500*16
    const int j = lane;                                      // output channel

    __shared__ __align__(16) float s_h[EW_WAVES][2][HID];      // 2 KB
    __shared__ __align__(16) float s_g[EW_WAVES][EPW][HID];    // 16 KB
    float* __restrict__ sh0 = s_h[wv][0];
    float* __restrict__ sh1 = s_h[wv][1];

    // ---- setup: my lane's edge (lanes 0..EPW-1 only) ----
    float ea[EDGE_DIM] = {0.f, 0.f, 0.f, 0.f, 0.f, 0.f, 0.f, 0.f};
    int p_mine = 0;
    if (lane < EPW) {
        const long em = base + lane;
        const float4 a0 = *(const float4*)&edge_attr[em * EDGE_DIM + 0];
        const float4 a1 = *(const float4*)&edge_attr[em * EDGE_DIM + 4];
        ea[0] = a0.x; ea[1] = a0.y; ea[2] = a0.z; ea[3] = a0.w;
        ea[4] = a1.x; ea[5] = a1.y; ea[6] = a1.z; ea[7] = a1.w;
        p_mine = atomicAdd(&cursor[dst_idx[em]], 1);
    }

    // ================= phase A: h2 for EPW edges -> s_g =================
    {
        float w1c[EDGE_DIM], w2c[HID];
#pragma unroll
        for (int k = 0; k < EDGE_DIM; ++k) w1c[k] = w1[k * HID + j];
#pragma unroll
        for (int k = 0; k < HID; ++k) w2c[k] = w2[k * HID + j];
#pragma unroll
        for (int k = 0; k < HID; ++k) asm volatile("" : "+v"(w2c[k]));
        const float b1j = b1[j], b2j = b2[j];

#pragma unroll 1
        for (int e = 0; e < EPW; e += 2) {
            // L1: readlane broadcast (8 k-values)
            float A0 = b1j, A1 = b1j;
#pragma unroll
            for (int k = 0; k < EDGE_DIM; ++k) {
                A0 = fmaf(rlanef(ea[k], e),     w1c[k], A0);
                A1 = fmaf(rlanef(ea[k], e + 1), w1c[k], A1);
            }
            sh0[j] = fmaxf(A0, 0.f);
            sh1[j] = fmaxf(A1, 0.f);

            // L2: h via LDS float4 broadcast
            float B0a = b2j, B0b = 0.f, B1a = b2j, B1b = 0.f;
#pragma unroll
            for (int kk = 0; kk < HID / 4; ++kk) {
                const float4 h0 = *(const float4*)&sh0[kk * 4];
                const float4 h1 = *(const float4*)&sh1[kk * 4];
                B0a = fmaf(h0.x, w2c[kk * 4 + 0], B0a);
                B0b = fmaf(h0.y, w2c[kk * 4 + 1], B0b);
                B0a = fmaf(h0.z, w2c[kk * 4 + 2], B0a);
                B0b = fmaf(h0.w, w2c[kk * 4 + 3], B0b);
                B1a = fmaf(h1.x, w2c[kk * 4 + 0], B1a);
                B1b = fmaf(h1.y, w2c[kk * 4 + 1], B1b);
                B1a = fmaf(h1.z, w2c[kk * 4 + 2], B1a);
                B1b = fmaf(h1.w, w2c[kk * 4 + 3], B1b);
            }
            s_g[wv][e][j]     = fmaxf(B0a + B0b, 0.f);
            s_g[wv][e + 1][j] = fmaxf(B1a + B1b, 0.f);
        }
    }

    // ================= phase B: msg = g @ W3p + b3p =================
    {
        float w3c[HID];
#pragma unroll
        for (int k = 0; k < HID; ++k) w3c[k] = W3p[k * HID + j];
#pragma unroll
        for (int k = 0; k < HID; ++k) asm volatile("" : "+v"(w3c[k]));
        const float b3j = b3p[j];

#pragma unroll 1
        for (int e = 0; e < EPW; e += 2) {
            const float* __restrict__ g0 = s_g[wv][e];
            const float* __restrict__ g1 = s_g[wv][e + 1];
            float C0a = b3j, C0b = 0.f, C1a = b3j, C1b = 0.f;
#pragma unroll
            for (int kk = 0; kk < HID / 4; ++kk) {
                const float4 v0 = *(const float4*)&g0[kk * 4];
                const float4 v1 = *(const float4*)&g1[kk * 4];
                C0a = fmaf(v0.x, w3c[kk * 4 + 0], C0a);
                C0b = fmaf(v0.y, w3c[kk * 4 + 1], C0b);
                C0a = fmaf(v0.z, w3c[kk * 4 + 2], C0a);
                C0b = fmaf(v0.w, w3c[kk * 4 + 3], C0b);
                C1a = fmaf(v1.x, w3c[kk * 4 + 0], C1a);
                C1b = fmaf(v1.y, w3c[kk * 4 + 1], C1b);
                C1a = fmaf(v1.z, w3c[kk * 4 + 2], C1a);
                C1b = fmaf(v1.w, w3c[kk * 4 + 3], C1b);
            }
            const int p0 = __builtin_amdgcn_readlane(p_mine, e);
            const int p1 = __builtin_amdgcn_readlane(p_mine, e + 1);
            msg_buf[(long)p0 * HID + j] = C0a + C0b;
            msg_buf[(long)p1 * HID + j] = C1a + C1b;
        }
    }
}

// ---------------------------------------------------------------------------
// Kernel E: gather msg rows per node, +r, relu, per-graph pooled sums/counts.
// One wave per 8 nodes; lane = hid channel; batch sorted -> run accumulation.
// ---------------------------------------------------------------------------
#define GN_PER_WAVE 8
__global__ __launch_bounds__(256) void gather_kernel(
    const float* __restrict__ msg_buf, const int* __restrict__ start,
    const float* __restrict__ r, const int* __restrict__ batch,
    float* __restrict__ sums, float* __restrict__ counts_f)
{
    const int wave = threadIdx.x >> 6;
    const int j    = threadIdx.x & 63;
    const int n0   = blockIdx.x * (4 * GN_PER_WAVE) + wave * GN_PER_WAVE;
    if (n0 >= N_NODES) return;
    const int n1 = min(n0 + GN_PER_WAVE, N_NODES);
    const float rj = r[j];

    int   g    = batch[n0];
    float pacc = 0.f, cnt = 0.f;
    for (int n = n0; n < n1; ++n) {
        const int gn = batch[n];
        if (gn != g) {
            unsafeAtomicAdd(&sums[g * HID + j], pacc);
            if (j == 0) unsafeAtomicAdd(&counts_f[g], cnt);
            g = gn; pacc = 0.f; cnt = 0.f;
        }
        float acc = 0.f;
        const int p0 = start[n], p1 = start[n + 1];
        for (int p = p0; p < p1; ++p)
            acc += msg_buf[(long)p * HID + j];
        pacc += fmaxf(acc + rj, 0.f);
        cnt  += 1.f;
    }
    unsafeAtomicAdd(&sums[g * HID + j], pacc);
    if (j == 0) unsafeAtomicAdd(&counts_f[g], cnt);
}

// ---------------------------------------------------------------------------
// Kernel F: classifier head. One block (128 threads) per graph.
// ---------------------------------------------------------------------------
__global__ __launch_bounds__(128) void head_kernel(
    const float* __restrict__ sums, const float* __restrict__ counts,
    const float* __restrict__ l1_w, const float* __restrict__ l1_b,
    const float* __restrict__ l2_w, const float* __restrict__ l2_b,
    float* __restrict__ out)
{
    const int g = blockIdx.x;
    const int t = threadIdx.x;
    __shared__ float pooled[HID];
    __shared__ float hid[2 * HID];

    const float cnt = fmaxf(counts[g], 1.0f);
    if (t < HID) pooled[t] = sums[g * HID + t] / cnt;
    __syncthreads();

    float a = l1_b[t];
#pragma unroll
    for (int k = 0; k < HID; ++k)
        a = fmaf(pooled[k], l1_w[k * (2 * HID) + t], a);
    hid[t] = fmaxf(a, 0.f);
    __syncthreads();

    if (t < OUT_DIM) {
        float o = l2_b[t];
#pragma unroll
        for (int k = 0; k < 2 * HID; ++k)
            o = fmaf(hid[k], l2_w[k * OUT_DIM + t], o);
        out[g * OUT_DIM + t] = o;
    }
}

// ---------------------------------------------------------------------------
extern "C" void kernel_launch(void* const* d_in, const int* in_sizes, int n_in,
                              void* d_out, int out_size, void* d_ws, size_t ws_size,
                              hipStream_t stream) {
    const float* edge_attr = (const float*)d_in[0];
    const int*   edge_idx  = (const int*)d_in[1];
    const int*   batch     = (const int*)d_in[2];
    const float* node_emb  = (const float*)d_in[3];
    const float* w1        = (const float*)d_in[4];
    const float* b1        = (const float*)d_in[5];
    const float* w2        = (const float*)d_in[6];
    const float* b2        = (const float*)d_in[7];
    const float* w3        = (const float*)d_in[8];
    const float* b3        = (const float*)d_in[9];
    const float* root_w    = (const float*)d_in[10];
    const float* conv_b    = (const float*)d_in[11];
    const float* l1_w      = (const float*)d_in[12];
    const float* l1_b      = (const float*)d_in[13];
    const float* l2_w      = (const float*)d_in[14];
    const float* l2_b      = (const float*)d_in[15];
    float* out = (float*)d_out;

    // workspace layout
    float* ws     = (float*)d_ws;
    float* W3p    = ws;                          // 4096
    float* b3p    = W3p + HID * HID;             // 64
    float* r      = b3p + HID;                   // 64
    float* sums   = r + HID;                     // 128*64
    float* cts    = sums + N_GRAPHS * HID;       // 128
    int*   counts = (int*)(cts + N_GRAPHS);      // 20000
    int*   startp = counts + N_NODES;            // 20001
    int*   cursor = startp + (N_NODES + 1);      // 20000
    int*   tot    = cursor + N_NODES;            // 20
    int*   off    = tot + SCAN_NBLK;             // 20
    float* msg    = (float*)(off + SCAN_NBLK);   // 200000*64 floats (51.2 MB)

    // zero sums/cts/counts (contiguous region)
    hipMemsetAsync(sums, 0,
                   (size_t)(N_GRAPHS * HID + N_GRAPHS + N_NODES) * 4, stream);

    const int* dst_idx = edge_idx + N_EDGES;   // edge_index[1]

    combo_kernel<<<16 + (N_EDGES + 255) / 256, 256, 0, stream>>>(
        node_emb, w3, b3, root_w, conv_b, dst_idx, W3p, b3p, r, counts);

    scanA_kernel<<<SCAN_NBLK, 1024, 0, stream>>>(counts, startp, tot);
    scanB_kernel<<<1, 64, 0, stream>>>(tot, off);
    scanC_kernel<<<SCAN_NBLK, 1024, 0, stream>>>(startp, cursor, off);

    edge_kernel<<<(N_EDGES / EPW + EW_WAVES - 1) / EW_WAVES, 64 * EW_WAVES, 0, stream>>>(
        edge_attr, dst_idx, w1, b1, w2, b2, W3p, b3p, cursor, msg);

    gather_kernel<<<(N_NODES + 4 * GN_PER_WAVE - 1) / (4 * GN_PER_WAVE), 256, 0, stream>>>(
        msg, startp, r, batch, sums, cts);

    head_kernel<<<N_GRAPHS, 128, 0, stream>>>(
        sums, cts, l1_w, l1_b, l2_w, l2_b, out);
}

// Round 14
// 97.343 us; speedup vs baseline: 2.8611x; 1.5705x over previous
//
#include <hip/hip_runtime.h>
#include <hip/hip_bf16.h>
#include <hip/amd_detail/amd_hip_unsafe_atomics.h>

#define N_EDGES 200000
#define N_NODES 20000
#define N_GRAPHS 128
#define IN_DIM 16
#define EDGE_DIM 8
#define HID 64
#define OUT_DIM 10
#define SCAN_NBLK ((N_NODES + 1023) / 1024)   // 20
#define N_TILES (N_EDGES / 16)                // 12500 tiles of 16 edges
#define TPW 2                                 // tiles per wave
#define N_EWAVES (N_TILES / TPW)              // 6250

typedef __attribute__((ext_vector_type(8))) short bf16x8;
typedef __attribute__((ext_vector_type(4))) float f32x4;

__device__ __forceinline__ ushort f2bf(float x) {
    unsigned b = __float_as_uint(x);
    return (ushort)((b + 0x7FFFu + ((b >> 16) & 1u)) >> 16);
}
__device__ __forceinline__ float bf2f(ushort u) {
    return __uint_as_float(((unsigned)u) << 16);
}

// ---------------------------------------------------------------------------
// Kernel A (combo): blocks 0..15  = precompute W3p/b3p/r,
//                   blocks 16..63 = pack w1,w2 into MFMA B-frag bf16 hi/lo,
//                   blocks 64..   = histogram of dst.
// B-frag layout (16x16x32): lane holds n = t*16 + lane%16, k = f*32 + 8*(lane/16)+i
// fw1: [t][h][lane][i]  (k-frag f=0 only, k>=8 zero)   4096 ushort
// fw2: [t][f][h][lane][i]                              8192 ushort
// ---------------------------------------------------------------------------
__global__ __launch_bounds__(256) void combo_kernel(
    const float* __restrict__ emb, const float* __restrict__ w3,
    const float* __restrict__ b3, const float* __restrict__ root_w,
    const float* __restrict__ conv_b, const int* __restrict__ dst_idx,
    const float* __restrict__ w1, const float* __restrict__ w2,
    float* __restrict__ W3p, float* __restrict__ b3p, float* __restrict__ r,
    ushort* __restrict__ fw1, ushort* __restrict__ fw2,
    int* __restrict__ counts)
{
    if (blockIdx.x < 16) {
        int t = blockIdx.x * 256 + threadIdx.x;   // 0..4095
        int k = t >> 6;
        int h = t & 63;
        float acc = 0.f;
#pragma unroll
        for (int i = 0; i < IN_DIM; ++i)
            acc = fmaf(emb[i], w3[k * (IN_DIM * HID) + i * HID + h], acc);
        W3p[t] = acc;
        if (t < HID) {
            float a = 0.f, rr = 0.f;
#pragma unroll
            for (int i = 0; i < IN_DIM; ++i) {
                a  = fmaf(emb[i], b3[i * HID + t], a);
                rr = fmaf(emb[i], root_w[i * HID + t], rr);
            }
            b3p[t] = a;
            r[t]   = rr + conv_b[t];
        }
    } else if (blockIdx.x < 64) {
        int idx  = (blockIdx.x - 16) * 256 + threadIdx.x;  // 0..12287
        int frag = idx >> 9;
        int rem  = idx & 511;
        int lane = rem >> 3, i = rem & 7;
        int q = lane >> 4, n16 = lane & 15;
        if (frag < 8) {
            int t = frag >> 1, h = frag & 1;
            int k = 8 * q + i, n = t * 16 + n16;
            float v = (k < EDGE_DIM) ? w1[k * HID + n] : 0.f;
            ushort hi = f2bf(v);
            fw1[((t * 2 + h) * 64 + lane) * 8 + i] =
                (h == 0) ? hi : f2bf(v - bf2f(hi));
        } else {
            int u = frag - 8;
            int t = u >> 2, f = (u >> 1) & 1, h = u & 1;
            int k = f * 32 + 8 * q + i, n = t * 16 + n16;
            float v = w2[k * HID + n];
            ushort hi = f2bf(v);
            fw2[(((t * 2 + f) * 2 + h) * 64 + lane) * 8 + i] =
                (h == 0) ? hi : f2bf(v - bf2f(hi));
        }
    } else {
        int e = (blockIdx.x - 64) * 256 + threadIdx.x;
        if (e < N_EDGES) atomicAdd(&counts[dst_idx[e]], 1);
    }
}

// ---------------------------------------------------------------------------
// Kernel 2a/2b/2c: multi-block scan; scanA's extra blocks pack W3p frags.
// ---------------------------------------------------------------------------
__global__ __launch_bounds__(1024) void scanA_kernel(
    const int* __restrict__ counts, int* __restrict__ start, int* __restrict__ tot,
    const float* __restrict__ W3p, ushort* __restrict__ fw3)
{
    const int b = blockIdx.x, t = threadIdx.x;
    if (b >= SCAN_NBLK) {                       // blocks 20..27: fw3 prep
        int idx  = (b - SCAN_NBLK) * 1024 + t;  // 0..8191
        int u    = idx >> 9;
        int rem  = idx & 511;
        int lane = rem >> 3, i = rem & 7;
        int tt = u >> 2, f = (u >> 1) & 1, h = u & 1;
        int k = f * 32 + 8 * (lane >> 4) + i, n = tt * 16 + (lane & 15);
        float v = W3p[k * HID + n];
        ushort hi = f2bf(v);
        fw3[(((tt * 2 + f) * 2 + h) * 64 + lane) * 8 + i] =
            (h == 0) ? hi : f2bf(v - bf2f(hi));
        return;
    }
    const int i = b * 1024 + t;
    const int v = (i < N_NODES) ? counts[i] : 0;
    const int lane = t & 63, wid = t >> 6;
    __shared__ int wsum[16];
    int incl = v;
#pragma unroll
    for (int off = 1; off < 64; off <<= 1) {
        int u = __shfl_up(incl, off, 64);
        if (lane >= off) incl += u;
    }
    if (lane == 63) wsum[wid] = incl;
    __syncthreads();
    if (wid == 0) {
        int wv = (lane < 16) ? wsum[lane] : 0;
        int wi = wv;
#pragma unroll
        for (int off = 1; off < 16; off <<= 1) {
            int u = __shfl_up(wi, off, 64);
            if (lane >= off) wi += u;
        }
        if (lane < 16) wsum[lane] = wi - wv;
    }
    __syncthreads();
    const int excl = wsum[wid] + incl - v;
    if (i < N_NODES) start[i] = excl;
    if (t == 1023) tot[b] = excl + v;
}

__global__ __launch_bounds__(64) void scanB_kernel(int* __restrict__ tot,
                                                   int* __restrict__ off)
{
    const int t = threadIdx.x;
    int v = (t < SCAN_NBLK) ? tot[t] : 0;
    int incl = v;
#pragma unroll
    for (int o = 1; o < 64; o <<= 1) {
        int u = __shfl_up(incl, o, 64);
        if (t >= o) incl += u;
    }
    if (t < SCAN_NBLK) off[t] = incl - v;
}

__global__ __launch_bounds__(1024) void scanC_kernel(
    int* __restrict__ start, int* __restrict__ cursor, const int* __restrict__ off)
{
    const int b = blockIdx.x, t = threadIdx.x;
    const int i = b * 1024 + t;
    if (i < N_NODES) {
        const int s = start[i] + off[b];
        start[i]  = s;
        cursor[i] = s;
    }
    if (b == 0 && t == 0) start[N_NODES] = N_EDGES;
}

// ---------------------------------------------------------------------------
// Kernel D: edge MLP on matrix cores, split-bf16 (hi+lo; 3 MFMA per product
// => ~2^-18 relative error, well under threshold). Wave owns TPW tiles of 16
// edges. A-frag: m=lane%16, k=8*(lane/16)+i. C-frag (m89-verified):
// n=lane&15, m=(lane>>4)*4+reg. Inter-layer: relu'd activations written to
// wave-private LDS as bf16 hi/lo, re-read with ds_read_b128 directly as the
// next layer's A-frags (no cvt on read, no barriers).
// ---------------------------------------------------------------------------
__global__ __launch_bounds__(256) void edge_mfma_kernel(
    const float* __restrict__ edge_attr, const int* __restrict__ dst_idx,
    const ushort* __restrict__ fw1, const ushort* __restrict__ fw2,
    const ushort* __restrict__ fw3,
    const float* __restrict__ b1, const float* __restrict__ b2,
    const float* __restrict__ b3p,
    int* __restrict__ cursor, float* __restrict__ msg_buf)
{
    const int lane = threadIdx.x & 63;
    const int wv   = threadIdx.x >> 6;
    const int gw   = blockIdx.x * 4 + wv;
    const int tile0 = gw * TPW;
    if (tile0 >= N_TILES) return;
    const int q = lane >> 4, l16 = lane & 15;

    __shared__ ushort s_hi[4][TPW][16][72];
    __shared__ ushort s_lo[4][TPW][16][72];

    // biases in C-layout (depend on channel n = t*16 + l16 only)
    float bb1[4], bb2[4], bb3[4];
#pragma unroll
    for (int t = 0; t < 4; ++t) {
        bb1[t] = b1[t * 16 + l16];
        bb2[t] = b2[t * 16 + l16];
        bb3[t] = b3p[t * 16 + l16];
    }

    // per-tile edge attrs + sorted slot (lanes 0..15 own one edge each)
    float e8[TPW][8];
    int   p_mine[TPW];
#pragma unroll
    for (int tt = 0; tt < TPW; ++tt) {
        p_mine[tt] = 0;
#pragma unroll
        for (int i = 0; i < 8; ++i) e8[tt][i] = 0.f;
        if (lane < 16) {
            const long em = (long)(tile0 + tt) * 16 + lane;
            const float4 A = *(const float4*)&edge_attr[em * EDGE_DIM + 0];
            const float4 B = *(const float4*)&edge_attr[em * EDGE_DIM + 4];
            e8[tt][0] = A.x; e8[tt][1] = A.y; e8[tt][2] = A.z; e8[tt][3] = A.w;
            e8[tt][4] = B.x; e8[tt][5] = B.y; e8[tt][6] = B.z; e8[tt][7] = B.w;
            p_mine[tt] = atomicAdd(&cursor[dst_idx[em]], 1);
        }
    }

    // ================= phase 1: L1 (K=8, zero-padded to 32) =================
    {
        bf16x8 w1h[4], w1l[4];
#pragma unroll
        for (int t = 0; t < 4; ++t) {
            w1h[t] = ((const bf16x8*)fw1)[(t * 2 + 0) * 64 + lane];
            w1l[t] = ((const bf16x8*)fw1)[(t * 2 + 1) * 64 + lane];
        }
#pragma unroll
        for (int tt = 0; tt < TPW; ++tt) {
            bf16x8 a1h, a1l;
#pragma unroll
            for (int i = 0; i < 8; ++i) {
                const ushort hi = f2bf(e8[tt][i]);
                a1h[i] = (short)hi;
                a1l[i] = (short)f2bf(e8[tt][i] - bf2f(hi));
            }
#pragma unroll
            for (int t = 0; t < 4; ++t) {
                f32x4 c = {0.f, 0.f, 0.f, 0.f};
                c = __builtin_amdgcn_mfma_f32_16x16x32_bf16(a1l, w1h[t], c, 0, 0, 0);
                c = __builtin_amdgcn_mfma_f32_16x16x32_bf16(a1h, w1l[t], c, 0, 0, 0);
                c = __builtin_amdgcn_mfma_f32_16x16x32_bf16(a1h, w1h[t], c, 0, 0, 0);
#pragma unroll
                for (int rr = 0; rr < 4; ++rr) {
                    float x = fmaxf(c[rr] + bb1[t], 0.f);
                    const ushort hi = f2bf(x);
                    s_hi[wv][tt][q * 4 + rr][t * 16 + l16] = hi;
                    s_lo[wv][tt][q * 4 + rr][t * 16 + l16] = f2bf(x - bf2f(hi));
                }
            }
        }
    }

    // ================= phase 2: L2 (K=64) =================
    {
        bf16x8 w2h[4][2], w2l[4][2];
#pragma unroll
        for (int t = 0; t < 4; ++t)
#pragma unroll
            for (int f = 0; f < 2; ++f) {
                w2h[t][f] = ((const bf16x8*)fw2)[((t * 2 + f) * 2 + 0) * 64 + lane];
                w2l[t][f] = ((const bf16x8*)fw2)[((t * 2 + f) * 2 + 1) * 64 + lane];
            }
#pragma unroll
        for (int tt = 0; tt < TPW; ++tt) {
            bf16x8 a2h[2], a2l[2];
#pragma unroll
            for (int f = 0; f < 2; ++f) {
                a2h[f] = *(const bf16x8*)&s_hi[wv][tt][l16][f * 32 + 8 * q];
                a2l[f] = *(const bf16x8*)&s_lo[wv][tt][l16][f * 32 + 8 * q];
            }
            f32x4 cc[4];
#pragma unroll
            for (int t = 0; t < 4; ++t) {
                f32x4 c = {0.f, 0.f, 0.f, 0.f};
#pragma unroll
                for (int f = 0; f < 2; ++f) {
                    c = __builtin_amdgcn_mfma_f32_16x16x32_bf16(a2l[f], w2h[t][f], c, 0, 0, 0);
                    c = __builtin_amdgcn_mfma_f32_16x16x32_bf16(a2h[f], w2l[t][f], c, 0, 0, 0);
                    c = __builtin_amdgcn_mfma_f32_16x16x32_bf16(a2h[f], w2h[t][f], c, 0, 0, 0);
                }
                cc[t] = c;
            }
#pragma unroll
            for (int t = 0; t < 4; ++t)
#pragma unroll
                for (int rr = 0; rr < 4; ++rr) {
                    float x = fmaxf(cc[t][rr] + bb2[t], 0.f);
                    const ushort hi = f2bf(x);
                    s_hi[wv][tt][q * 4 + rr][t * 16 + l16] = hi;
                    s_lo[wv][tt][q * 4 + rr][t * 16 + l16] = f2bf(x - bf2f(hi));
                }
        }
    }

    // ================= phase 3: L3 (K=64) + store =================
    {
        bf16x8 w3h[4][2], w3l[4][2];
#pragma unroll
        for (int t = 0; t < 4; ++t)
#pragma unroll
            for (int f = 0; f < 2; ++f) {
                w3h[t][f] = ((const bf16x8*)fw3)[((t * 2 + f) * 2 + 0) * 64 + lane];
                w3l[t][f] = ((const bf16x8*)fw3)[((t * 2 + f) * 2 + 1) * 64 + lane];
            }
#pragma unroll
        for (int tt = 0; tt < TPW; ++tt) {
            bf16x8 a3h[2], a3l[2];
#pragma unroll
            for (int f = 0; f < 2; ++f) {
                a3h[f] = *(const bf16x8*)&s_hi[wv][tt][l16][f * 32 + 8 * q];
                a3l[f] = *(const bf16x8*)&s_lo[wv][tt][l16][f * 32 + 8 * q];
            }
            f32x4 cc[4];
#pragma unroll
            for (int t = 0; t < 4; ++t) {
                f32x4 c = {0.f, 0.f, 0.f, 0.f};
#pragma unroll
                for (int f = 0; f < 2; ++f) {
                    c = __builtin_amdgcn_mfma_f32_16x16x32_bf16(a3l[f], w3h[t][f], c, 0, 0, 0);
                    c = __builtin_amdgcn_mfma_f32_16x16x32_bf16(a3h[f], w3l[t][f], c, 0, 0, 0);
                    c = __builtin_amdgcn_mfma_f32_16x16x32_bf16(a3h[f], w3h[t][f], c, 0, 0, 0);
                }
                cc[t] = c;
            }
            int p_r[4];
#pragma unroll
            for (int rr = 0; rr < 4; ++rr)
                p_r[rr] = __shfl(p_mine[tt], q * 4 + rr);
#pragma unroll
            for (int t = 0; t < 4; ++t)
#pragma unroll
                for (int rr = 0; rr < 4; ++rr)
                    msg_buf[(long)p_r[rr] * HID + t * 16 + l16] = cc[t][rr] + bb3[t];
        }
    }
}

// ---------------------------------------------------------------------------
// Kernel E: gather msg rows per node, +r, relu, per-graph pooled sums/counts.
// ---------------------------------------------------------------------------
#define GN_PER_WAVE 8
__global__ __launch_bounds__(256) void gather_kernel(
    const float* __restrict__ msg_buf, const int* __restrict__ start,
    const float* __restrict__ r, const int* __restrict__ batch,
    float* __restrict__ sums, float* __restrict__ counts_f)
{
    const int wave = threadIdx.x >> 6;
    const int j    = threadIdx.x & 63;
    const int n0   = blockIdx.x * (4 * GN_PER_WAVE) + wave * GN_PER_WAVE;
    if (n0 >= N_NODES) return;
    const int n1 = min(n0 + GN_PER_WAVE, N_NODES);
    const float rj = r[j];

    int   g    = batch[n0];
    float pacc = 0.f, cnt = 0.f;
    for (int n = n0; n < n1; ++n) {
        const int gn = batch[n];
        if (gn != g) {
            unsafeAtomicAdd(&sums[g * HID + j], pacc);
            if (j == 0) unsafeAtomicAdd(&counts_f[g], cnt);
            g = gn; pacc = 0.f; cnt = 0.f;
        }
        float acc = 0.f;
        const int p0 = start[n], p1 = start[n + 1];
        for (int p = p0; p < p1; ++p)
            acc += msg_buf[(long)p * HID + j];
        pacc += fmaxf(acc + rj, 0.f);
        cnt  += 1.f;
    }
    unsafeAtomicAdd(&sums[g * HID + j], pacc);
    if (j == 0) unsafeAtomicAdd(&counts_f[g], cnt);
}

// ---------------------------------------------------------------------------
// Kernel F: classifier head. One block (128 threads) per graph.
// ---------------------------------------------------------------------------
__global__ __launch_bounds__(128) void head_kernel(
    const float* __restrict__ sums, const float* __restrict__ counts,
    const float* __restrict__ l1_w, const float* __restrict__ l1_b,
    const float* __restrict__ l2_w, const float* __restrict__ l2_b,
    float* __restrict__ out)
{
    const int g = blockIdx.x;
    const int t = threadIdx.x;
    __shared__ float pooled[HID];
    __shared__ float hid[2 * HID];

    const float cnt = fmaxf(counts[g], 1.0f);
    if (t < HID) pooled[t] = sums[g * HID + t] / cnt;
    __syncthreads();

    float a = l1_b[t];
#pragma unroll
    for (int k = 0; k < HID; ++k)
        a = fmaf(pooled[k], l1_w[k * (2 * HID) + t], a);
    hid[t] = fmaxf(a, 0.f);
    __syncthreads();

    if (t < OUT_DIM) {
        float o = l2_b[t];
#pragma unroll
        for (int k = 0; k < 2 * HID; ++k)
            o = fmaf(hid[k], l2_w[k * OUT_DIM + t], o);
        out[g * OUT_DIM + t] = o;
    }
}

// ---------------------------------------------------------------------------
extern "C" void kernel_launch(void* const* d_in, const int* in_sizes, int n_in,
                              void* d_out, int out_size, void* d_ws, size_t ws_size,
                              hipStream_t stream) {
    const float* edge_attr = (const float*)d_in[0];
    const int*   edge_idx  = (const int*)d_in[1];
    const int*   batch     = (const int*)d_in[2];
    const float* node_emb  = (const float*)d_in[3];
    const float* w1        = (const float*)d_in[4];
    const float* b1        = (const float*)d_in[5];
    const float* w2        = (const float*)d_in[6];
    const float* b2        = (const float*)d_in[7];
    const float* w3        = (const float*)d_in[8];
    const float* b3        = (const float*)d_in[9];
    const float* root_w    = (const float*)d_in[10];
    const float* conv_b    = (const float*)d_in[11];
    const float* l1_w      = (const float*)d_in[12];
    const float* l1_b      = (const float*)d_in[13];
    const float* l2_w      = (const float*)d_in[14];
    const float* l2_b      = (const float*)d_in[15];
    float* out = (float*)d_out;

    // workspace layout
    float* ws     = (float*)d_ws;
    float* W3p    = ws;                          // 4096
    float* b3p    = W3p + HID * HID;             // 64
    float* r      = b3p + HID;                   // 64
    float* sums   = r + HID;                     // 128*64
    float* cts    = sums + N_GRAPHS * HID;       // 128
    int*   counts = (int*)(cts + N_GRAPHS);      // 20000
    int*   startp = counts + N_NODES;            // 20001
    int*   cursor = startp + (N_NODES + 1);      // 20000
    int*   tot    = cursor + N_NODES;            // 20
    int*   off    = tot + SCAN_NBLK;             // 20
    ushort* fw1 = (ushort*)(((uintptr_t)(off + SCAN_NBLK) + 15) & ~(uintptr_t)15);
    ushort* fw2 = fw1 + 4096;                    // 8 frags  * 512
    ushort* fw3 = fw2 + 8192;                    // 16 frags * 512
    float* msg  = (float*)(fw3 + 8192);          // 200000*64 floats (51.2 MB)

    // zero sums/cts/counts (contiguous region)
    hipMemsetAsync(sums, 0,
                   (size_t)(N_GRAPHS * HID + N_GRAPHS + N_NODES) * 4, stream);

    const int* dst_idx = edge_idx + N_EDGES;   // edge_index[1]

    combo_kernel<<<64 + (N_EDGES + 255) / 256, 256, 0, stream>>>(
        node_emb, w3, b3, root_w, conv_b, dst_idx, w1, w2,
        W3p, b3p, r, fw1, fw2, counts);

    scanA_kernel<<<SCAN_NBLK + 8, 1024, 0, stream>>>(counts, startp, tot, W3p, fw3);
    scanB_kernel<<<1, 64, 0, stream>>>(tot, off);
    scanC_kernel<<<SCAN_NBLK, 1024, 0, stream>>>(startp, cursor, off);

    edge_mfma_kernel<<<(N_EWAVES + 3) / 4, 256, 0, stream>>>(
        edge_attr, dst_idx, fw1, fw2, fw3, b1, b2, b3p, cursor, msg);

    gather_kernel<<<(N_NODES + 4 * GN_PER_WAVE - 1) / (4 * GN_PER_WAVE), 256, 0, stream>>>(
        msg, startp, r, batch, sums, cts);

    head_kernel<<<N_GRAPHS, 128, 0, stream>>>(
        sums, cts, l1_w, l1_b, l2_w, l2_b, out);
}

// Round 16
// 94.423 us; speedup vs baseline: 2.9496x; 1.0309x over previous
//
#include <hip/hip_runtime.h>
#include <hip/hip_bf16.h>
#include <hip/amd_detail/amd_hip_unsafe_atomics.h>

#define N_EDGES 200000
#define N_NODES 20000
#define N_GRAPHS 128
#define IN_DIM 16
#define EDGE_DIM 8
#define HID 64
#define OUT_DIM 10
#define SCAN_NBLK ((N_NODES + 1023) / 1024)   // 20
#define N_TILES (N_EDGES / 16)                // 12500 tiles of 16 edges
#define TPW 2                                 // tiles per wave
#define N_EWAVES (N_TILES / TPW)              // 6250

typedef __attribute__((ext_vector_type(8))) short bf16x8;
typedef __attribute__((ext_vector_type(4))) float f32x4;

__device__ __forceinline__ ushort f2bf(float x) {
    unsigned b = __float_as_uint(x);
    return (ushort)((b + 0x7FFFu + ((b >> 16) & 1u)) >> 16);
}
__device__ __forceinline__ float bf2f(ushort u) {
    return __uint_as_float(((unsigned)u) << 16);
}

// ---------------------------------------------------------------------------
// Kernel A (combo): blocks 0..15  = precompute W3p/b3p/r,
//                   blocks 16..63 = pack w1,w2 into MFMA B-frag bf16 hi/lo,
//                   blocks 64..   = histogram of dst.
// ---------------------------------------------------------------------------
__global__ __launch_bounds__(256) void combo_kernel(
    const float* __restrict__ emb, const float* __restrict__ w3,
    const float* __restrict__ b3, const float* __restrict__ root_w,
    const float* __restrict__ conv_b, const int* __restrict__ dst_idx,
    const float* __restrict__ w1, const float* __restrict__ w2,
    float* __restrict__ W3p, float* __restrict__ b3p, float* __restrict__ r,
    ushort* __restrict__ fw1, ushort* __restrict__ fw2,
    int* __restrict__ counts)
{
    if (blockIdx.x < 16) {
        int t = blockIdx.x * 256 + threadIdx.x;   // 0..4095
        int k = t >> 6;
        int h = t & 63;
        float acc = 0.f;
#pragma unroll
        for (int i = 0; i < IN_DIM; ++i)
            acc = fmaf(emb[i], w3[k * (IN_DIM * HID) + i * HID + h], acc);
        W3p[t] = acc;
        if (t < HID) {
            float a = 0.f, rr = 0.f;
#pragma unroll
            for (int i = 0; i < IN_DIM; ++i) {
                a  = fmaf(emb[i], b3[i * HID + t], a);
                rr = fmaf(emb[i], root_w[i * HID + t], rr);
            }
            b3p[t] = a;
            r[t]   = rr + conv_b[t];
        }
    } else if (blockIdx.x < 64) {
        int idx  = (blockIdx.x - 16) * 256 + threadIdx.x;  // 0..12287
        int frag = idx >> 9;
        int rem  = idx & 511;
        int lane = rem >> 3, i = rem & 7;
        int q = lane >> 4, n16 = lane & 15;
        if (frag < 8) {
            int t = frag >> 1, h = frag & 1;
            int k = 8 * q + i, n = t * 16 + n16;
            float v = (k < EDGE_DIM) ? w1[k * HID + n] : 0.f;
            ushort hi = f2bf(v);
            fw1[((t * 2 + h) * 64 + lane) * 8 + i] =
                (h == 0) ? hi : f2bf(v - bf2f(hi));
        } else {
            int u = frag - 8;
            int t = u >> 2, f = (u >> 1) & 1, h = u & 1;
            int k = f * 32 + 8 * q + i, n = t * 16 + n16;
            float v = w2[k * HID + n];
            ushort hi = f2bf(v);
            fw2[(((t * 2 + f) * 2 + h) * 64 + lane) * 8 + i] =
                (h == 0) ? hi : f2bf(v - bf2f(hi));
        }
    } else {
        int e = (blockIdx.x - 64) * 256 + threadIdx.x;
        if (e < N_EDGES) atomicAdd(&counts[dst_idx[e]], 1);
    }
}

// ---------------------------------------------------------------------------
// scanA: block-local scan (+ extra blocks pack W3p frags).
// ---------------------------------------------------------------------------
__global__ __launch_bounds__(1024) void scanA_kernel(
    const int* __restrict__ counts, int* __restrict__ start, int* __restrict__ tot,
    const float* __restrict__ W3p, ushort* __restrict__ fw3)
{
    const int b = blockIdx.x, t = threadIdx.x;
    if (b >= SCAN_NBLK) {                       // blocks 20..27: fw3 prep
        int idx  = (b - SCAN_NBLK) * 1024 + t;  // 0..8191
        int u    = idx >> 9;
        int rem  = idx & 511;
        int lane = rem >> 3, i = rem & 7;
        int tt = u >> 2, f = (u >> 1) & 1, h = u & 1;
        int k = f * 32 + 8 * (lane >> 4) + i, n = tt * 16 + (lane & 15);
        float v = W3p[k * HID + n];
        ushort hi = f2bf(v);
        fw3[(((tt * 2 + f) * 2 + h) * 64 + lane) * 8 + i] =
            (h == 0) ? hi : f2bf(v - bf2f(hi));
        return;
    }
    const int i = b * 1024 + t;
    const int v = (i < N_NODES) ? counts[i] : 0;
    const int lane = t & 63, wid = t >> 6;
    __shared__ int wsum[16];
    int incl = v;
#pragma unroll
    for (int off = 1; off < 64; off <<= 1) {
        int u = __shfl_up(incl, off, 64);
        if (lane >= off) incl += u;
    }
    if (lane == 63) wsum[wid] = incl;
    __syncthreads();
    if (wid == 0) {
        int wv = (lane < 16) ? wsum[lane] : 0;
        int wi = wv;
#pragma unroll
        for (int off = 1; off < 16; off <<= 1) {
            int u = __shfl_up(wi, off, 64);
            if (lane >= off) wi += u;
        }
        if (lane < 16) wsum[lane] = wi - wv;
    }
    __syncthreads();
    const int excl = wsum[wid] + incl - v;
    if (i < N_NODES) start[i] = excl;
    if (t == 1023) tot[b] = excl + v;
}

// ---------------------------------------------------------------------------
// scanC (scanB folded in): block b sums tot[0..b-1] with a wave reduce, then
// applies the offset.
// ---------------------------------------------------------------------------
__global__ __launch_bounds__(1024) void scanC_kernel(
    int* __restrict__ start, int* __restrict__ cursor, const int* __restrict__ tot)
{
    __shared__ int s_off;
    const int b = blockIdx.x, t = threadIdx.x;
    if (t < 64) {
        int v = (t < b && t < SCAN_NBLK) ? tot[t] : 0;
#pragma unroll
        for (int o = 32; o >= 1; o >>= 1) v += __shfl_xor(v, o, 64);
        if (t == 0) s_off = v;
    }
    __syncthreads();
    const int i = b * 1024 + t;
    if (i < N_NODES) {
        const int s = start[i] + s_off;
        start[i]  = s;
        cursor[i] = s;
    }
    if (b == 0 && t == 0) start[N_NODES] = N_EDGES;
}

// ---------------------------------------------------------------------------
// Kernel D: edge MLP on matrix cores, split-bf16 (verified R13: absmax 3.8e-6).
// Output msg stored as bf16 (halves msg traffic; adds ~1e-5 node-level error,
// shrunk by mean-pool + head -> est. final ~1e-5, threshold 9.3e-5).
// ---------------------------------------------------------------------------
__global__ __launch_bounds__(256) void edge_mfma_kernel(
    const float* __restrict__ edge_attr, const int* __restrict__ dst_idx,
    const ushort* __restrict__ fw1, const ushort* __restrict__ fw2,
    const ushort* __restrict__ fw3,
    const float* __restrict__ b1, const float* __restrict__ b2,
    const float* __restrict__ b3p,
    int* __restrict__ cursor, ushort* __restrict__ msg16)
{
    const int lane = threadIdx.x & 63;
    const int wv   = threadIdx.x >> 6;
    const int gw   = blockIdx.x * 4 + wv;
    const int tile0 = gw * TPW;
    if (tile0 >= N_TILES) return;
    const int q = lane >> 4, l16 = lane & 15;

    __shared__ ushort s_hi[4][TPW][16][72];
    __shared__ ushort s_lo[4][TPW][16][72];

    float bb1[4], bb2[4], bb3[4];
#pragma unroll
    for (int t = 0; t < 4; ++t) {
        bb1[t] = b1[t * 16 + l16];
        bb2[t] = b2[t * 16 + l16];
        bb3[t] = b3p[t * 16 + l16];
    }

    float e8[TPW][8];
    int   p_mine[TPW];
#pragma unroll
    for (int tt = 0; tt < TPW; ++tt) {
        p_mine[tt] = 0;
#pragma unroll
        for (int i = 0; i < 8; ++i) e8[tt][i] = 0.f;
        if (lane < 16) {
            const long em = (long)(tile0 + tt) * 16 + lane;
            const float4 A = *(const float4*)&edge_attr[em * EDGE_DIM + 0];
            const float4 B = *(const float4*)&edge_attr[em * EDGE_DIM + 4];
            e8[tt][0] = A.x; e8[tt][1] = A.y; e8[tt][2] = A.z; e8[tt][3] = A.w;
            e8[tt][4] = B.x; e8[tt][5] = B.y; e8[tt][6] = B.z; e8[tt][7] = B.w;
            p_mine[tt] = atomicAdd(&cursor[dst_idx[em]], 1);
        }
    }

    // ---- phase 1: L1 (K=8 zero-padded) ----
    {
        bf16x8 w1h[4], w1l[4];
#pragma unroll
        for (int t = 0; t < 4; ++t) {
            w1h[t] = ((const bf16x8*)fw1)[(t * 2 + 0) * 64 + lane];
            w1l[t] = ((const bf16x8*)fw1)[(t * 2 + 1) * 64 + lane];
        }
#pragma unroll
        for (int tt = 0; tt < TPW; ++tt) {
            bf16x8 a1h, a1l;
#pragma unroll
            for (int i = 0; i < 8; ++i) {
                const ushort hi = f2bf(e8[tt][i]);
                a1h[i] = (short)hi;
                a1l[i] = (short)f2bf(e8[tt][i] - bf2f(hi));
            }
#pragma unroll
            for (int t = 0; t < 4; ++t) {
                f32x4 c = {0.f, 0.f, 0.f, 0.f};
                c = __builtin_amdgcn_mfma_f32_16x16x32_bf16(a1l, w1h[t], c, 0, 0, 0);
                c = __builtin_amdgcn_mfma_f32_16x16x32_bf16(a1h, w1l[t], c, 0, 0, 0);
                c = __builtin_amdgcn_mfma_f32_16x16x32_bf16(a1h, w1h[t], c, 0, 0, 0);
#pragma unroll
                for (int rr = 0; rr < 4; ++rr) {
                    float x = fmaxf(c[rr] + bb1[t], 0.f);
                    const ushort hi = f2bf(x);
                    s_hi[wv][tt][q * 4 + rr][t * 16 + l16] = hi;
                    s_lo[wv][tt][q * 4 + rr][t * 16 + l16] = f2bf(x - bf2f(hi));
                }
            }
        }
    }

    // ---- phase 2: L2 (K=64) ----
    {
        bf16x8 w2h[4][2], w2l[4][2];
#pragma unroll
        for (int t = 0; t < 4; ++t)
#pragma unroll
            for (int f = 0; f < 2; ++f) {
                w2h[t][f] = ((const bf16x8*)fw2)[((t * 2 + f) * 2 + 0) * 64 + lane];
                w2l[t][f] = ((const bf16x8*)fw2)[((t * 2 + f) * 2 + 1) * 64 + lane];
            }
#pragma unroll
        for (int tt = 0; tt < TPW; ++tt) {
            bf16x8 a2h[2], a2l[2];
#pragma unroll
            for (int f = 0; f < 2; ++f) {
                a2h[f] = *(const bf16x8*)&s_hi[wv][tt][l16][f * 32 + 8 * q];
                a2l[f] = *(const bf16x8*)&s_lo[wv][tt][l16][f * 32 + 8 * q];
            }
            f32x4 cc[4];
#pragma unroll
            for (int t = 0; t < 4; ++t) {
                f32x4 c = {0.f, 0.f, 0.f, 0.f};
#pragma unroll
                for (int f = 0; f < 2; ++f) {
                    c = __builtin_amdgcn_mfma_f32_16x16x32_bf16(a2l[f], w2h[t][f], c, 0, 0, 0);
                    c = __builtin_amdgcn_mfma_f32_16x16x32_bf16(a2h[f], w2l[t][f], c, 0, 0, 0);
                    c = __builtin_amdgcn_mfma_f32_16x16x32_bf16(a2h[f], w2h[t][f], c, 0, 0, 0);
                }
                cc[t] = c;
            }
#pragma unroll
            for (int t = 0; t < 4; ++t)
#pragma unroll
                for (int rr = 0; rr < 4; ++rr) {
                    float x = fmaxf(cc[t][rr] + bb2[t], 0.f);
                    const ushort hi = f2bf(x);
                    s_hi[wv][tt][q * 4 + rr][t * 16 + l16] = hi;
                    s_lo[wv][tt][q * 4 + rr][t * 16 + l16] = f2bf(x - bf2f(hi));
                }
        }
    }

    // ---- phase 3: L3 (K=64) + bf16 store ----
    {
        bf16x8 w3h[4][2], w3l[4][2];
#pragma unroll
        for (int t = 0; t < 4; ++t)
#pragma unroll
            for (int f = 0; f < 2; ++f) {
                w3h[t][f] = ((const bf16x8*)fw3)[((t * 2 + f) * 2 + 0) * 64 + lane];
                w3l[t][f] = ((const bf16x8*)fw3)[((t * 2 + f) * 2 + 1) * 64 + lane];
            }
#pragma unroll
        for (int tt = 0; tt < TPW; ++tt) {
            bf16x8 a3h[2], a3l[2];
#pragma unroll
            for (int f = 0; f < 2; ++f) {
                a3h[f] = *(const bf16x8*)&s_hi[wv][tt][l16][f * 32 + 8 * q];
                a3l[f] = *(const bf16x8*)&s_lo[wv][tt][l16][f * 32 + 8 * q];
            }
            f32x4 cc[4];
#pragma unroll
            for (int t = 0; t < 4; ++t) {
                f32x4 c = {0.f, 0.f, 0.f, 0.f};
#pragma unroll
                for (int f = 0; f < 2; ++f) {
                    c = __builtin_amdgcn_mfma_f32_16x16x32_bf16(a3l[f], w3h[t][f], c, 0, 0, 0);
                    c = __builtin_amdgcn_mfma_f32_16x16x32_bf16(a3h[f], w3l[t][f], c, 0, 0, 0);
                    c = __builtin_amdgcn_mfma_f32_16x16x32_bf16(a3h[f], w3h[t][f], c, 0, 0, 0);
                }
                cc[t] = c;
            }
            int p_r[4];
#pragma unroll
            for (int rr = 0; rr < 4; ++rr)
                p_r[rr] = __shfl(p_mine[tt], q * 4 + rr);
#pragma unroll
            for (int t = 0; t < 4; ++t)
#pragma unroll
                for (int rr = 0; rr < 4; ++rr)
                    msg16[(long)p_r[rr] * HID + t * 16 + l16] =
                        f2bf(cc[t][rr] + bb3[t]);
        }
    }
}

// ---------------------------------------------------------------------------
// Kernel E: gather bf16 msg rows per node, +r, relu, pooled sums/counts.
// ---------------------------------------------------------------------------
#define GN_PER_WAVE 8
__global__ __launch_bounds__(256) void gather_kernel(
    const ushort* __restrict__ msg16, const int* __restrict__ start,
    const float* __restrict__ r, const int* __restrict__ batch,
    float* __restrict__ sums, float* __restrict__ counts_f)
{
    const int wave = threadIdx.x >> 6;
    const int j    = threadIdx.x & 63;
    const int n0   = blockIdx.x * (4 * GN_PER_WAVE) + wave * GN_PER_WAVE;
    if (n0 >= N_NODES) return;
    const int n1 = min(n0 + GN_PER_WAVE, N_NODES);
    const float rj = r[j];

    int   g    = batch[n0];
    float pacc = 0.f, cnt = 0.f;
    for (int n = n0; n < n1; ++n) {
        const int gn = batch[n];
        if (gn != g) {
            unsafeAtomicAdd(&sums[g * HID + j], pacc);
            if (j == 0) unsafeAtomicAdd(&counts_f[g], cnt);
            g = gn; pacc = 0.f; cnt = 0.f;
        }
        float acc = 0.f;
        const int p0 = start[n], p1 = start[n + 1];
        for (int p = p0; p < p1; ++p)
            acc += bf2f(msg16[(long)p * HID + j]);
        pacc += fmaxf(acc + rj, 0.f);
        cnt  += 1.f;
    }
    unsafeAtomicAdd(&sums[g * HID + j], pacc);
    if (j == 0) unsafeAtomicAdd(&counts_f[g], cnt);
}

// ---------------------------------------------------------------------------
// Kernel F: classifier head. One block (128 threads) per graph.
// ---------------------------------------------------------------------------
__global__ __launch_bounds__(128) void head_kernel(
    const float* __restrict__ sums, const float* __restrict__ counts,
    const float* __restrict__ l1_w, const float* __restrict__ l1_b,
    const float* __restrict__ l2_w, const float* __restrict__ l2_b,
    float* __restrict__ out)
{
    const int g = blockIdx.x;
    const int t = threadIdx.x;
    __shared__ float pooled[HID];
    __shared__ float hid[2 * HID];

    const float cnt = fmaxf(counts[g], 1.0f);
    if (t < HID) pooled[t] = sums[g * HID + t] / cnt;
    __syncthreads();

    float a = l1_b[t];
#pragma unroll
    for (int k = 0; k < HID; ++k)
        a = fmaf(pooled[k], l1_w[k * (2 * HID) + t], a);
    hid[t] = fmaxf(a, 0.f);
    __syncthreads();

    if (t < OUT_DIM) {
        float o = l2_b[t];
#pragma unroll
        for (int k = 0; k < 2 * HID; ++k)
            o = fmaf(hid[k], l2_w[k * OUT_DIM + t], o);
        out[g * OUT_DIM + t] = o;
    }
}

// ---------------------------------------------------------------------------
extern "C" void kernel_launch(void* const* d_in, const int* in_sizes, int n_in,
                              void* d_out, int out_size, void* d_ws, size_t ws_size,
                              hipStream_t stream) {
    const float* edge_attr = (const float*)d_in[0];
    const int*   edge_idx  = (const int*)d_in[1];
    const int*   batch     = (const int*)d_in[2];
    const float* node_emb  = (const float*)d_in[3];
    const float* w1        = (const float*)d_in[4];
    const float* b1        = (const float*)d_in[5];
    const float* w2        = (const float*)d_in[6];
    const float* b2        = (const float*)d_in[7];
    const float* w3        = (const float*)d_in[8];
    const float* b3        = (const float*)d_in[9];
    const float* root_w    = (const float*)d_in[10];
    const float* conv_b    = (const float*)d_in[11];
    const float* l1_w      = (const float*)d_in[12];
    const float* l1_b      = (const float*)d_in[13];
    const float* l2_w      = (const float*)d_in[14];
    const float* l2_b      = (const float*)d_in[15];
    float* out = (float*)d_out;

    // workspace layout
    float* ws     = (float*)d_ws;
    float* W3p    = ws;                          // 4096
    float* b3p    = W3p + HID * HID;             // 64
    float* r      = b3p + HID;                   // 64
    float* sums   = r + HID;                     // 128*64
    float* cts    = sums + N_GRAPHS * HID;       // 128
    int*   counts = (int*)(cts + N_GRAPHS);      // 20000
    int*   startp = counts + N_NODES;            // 20001
    int*   cursor = startp + (N_NODES + 1);      // 20000
    int*   tot    = cursor + N_NODES;            // 20
    ushort* fw1 = (ushort*)(((uintptr_t)(tot + SCAN_NBLK) + 15) & ~(uintptr_t)15);
    ushort* fw2 = fw1 + 4096;                    // 8 frags  * 512
    ushort* fw3 = fw2 + 8192;                    // 16 frags * 512
    ushort* msg16 = fw3 + 8192;                  // 200000*64 ushorts (25.6 MB)

    // zero sums/cts/counts (contiguous region)
    hipMemsetAsync(sums, 0,
                   (size_t)(N_GRAPHS * HID + N_GRAPHS + N_NODES) * 4, stream);

    const int* dst_idx = edge_idx + N_EDGES;   // edge_index[1]

    combo_kernel<<<64 + (N_EDGES + 255) / 256, 256, 0, stream>>>(
        node_emb, w3, b3, root_w, conv_b, dst_idx, w1, w2,
        W3p, b3p, r, fw1, fw2, counts);

    scanA_kernel<<<SCAN_NBLK + 8, 1024, 0, stream>>>(counts, startp, tot, W3p, fw3);
    scanC_kernel<<<SCAN_NBLK, 1024, 0, stream>>>(startp, cursor, tot);

    edge_mfma_kernel<<<(N_EWAVES + 3) / 4, 256, 0, stream>>>(
        edge_attr, dst_idx, fw1, fw2, fw3, b1, b2, b3p, cursor, msg16);

    gather_kernel<<<(N_NODES + 4 * GN_PER_WAVE - 1) / (4 * GN_PER_WAVE), 256, 0, stream>>>(
        msg16, startp, r, batch, sums, cts);

    head_kernel<<<N_GRAPHS, 128, 0, stream>>>(
        sums, cts, l1_w, l1_b, l2_w, l2_b, out);
}